// Round 1
// 124.893 us; speedup vs baseline: 1.0219x; 1.0219x over previous
//
#include <hip/hip_runtime.h>

// NetVLAD: N=16, C=1024, P=1024, K=32. MFMA bf16 for both GEMMs (NT layout).
// Runtime dtype detection (fp32 vs bf16 inputs); fp32 accumulate throughout.
// This rev: LDS double-buffer + 1-chunk register prefetch + raw-barrier sync
// (no vmcnt drain) in both GEMM kernels; k_vlad 32-c tiles (grid 512, 2 blk/CU);
// memset folded into k_detect; k_factors folded into k_out. 4 dispatches total.
#define NB   16
#define CC   1024
#define PP   1024
#define KK   32
#define EPSF 1e-12f

typedef __attribute__((ext_vector_type(8))) short  bf16x8;
typedef __attribute__((ext_vector_type(4))) float  f32x4;

__device__ __forceinline__ float bf2f(unsigned short u) {
    union { unsigned int i; float f; } v; v.i = ((unsigned int)u) << 16; return v.f;
}
__device__ __forceinline__ unsigned short f2bf(float f) {
    union { float f; unsigned int i; } v; v.f = f;
    return (unsigned short)((v.i + 0x7fffu + ((v.i >> 16) & 1u)) >> 16);  // RNE
}

template <typename T> struct IO;
template <> struct IO<float> {
    static __device__ __forceinline__ float  ld (const float* p) { return *p; }
    static __device__ __forceinline__ float4 ld4(const float* p) { return *(const float4*)p; }
};
template <> struct IO<unsigned short> {
    static __device__ __forceinline__ float  ld (const unsigned short* p) { return bf2f(*p); }
    static __device__ __forceinline__ float4 ld4(const unsigned short* p) {
        const ushort4 u = *(const ushort4*)p;
        return make_float4(bf2f(u.x), bf2f(u.y), bf2f(u.z), bf2f(u.w));
    }
};

// Workgroup barrier WITHOUT the __syncthreads vmcnt(0) drain: each wave waits
// only its own LDS ops (lgkmcnt), so prefetch global loads stay in flight
// across the barrier. Empty clobber after the barrier pins later LDS reads.
__device__ __forceinline__ void wg_sync_fast() {
    asm volatile("s_waitcnt lgkmcnt(0)" ::: "memory");
    __builtin_amdgcn_s_barrier();
    asm volatile("" ::: "memory");
}

// ---------------------------------------------------------------------------
// K0: dtype detect + zero-init asum/ssqnk (2*NB*KK floats, contiguous).
// fp32 data read as ushorts has random low-mantissa halves -> bf16-exponents
// > 0x9F appear w/ prob ~0.37 each over 4096 samples.
// ---------------------------------------------------------------------------
__global__ __launch_bounds__(256) void k_detect(const unsigned short* __restrict__ xu,
                                                int* __restrict__ flag,
                                                float* __restrict__ zbuf) {
    __shared__ int s;
    const int t = threadIdx.x;
    for (int i = t; i < 2 * NB * KK; i += 256) zbuf[i] = 0.f;
    if (t == 0) s = 0;
    __syncthreads();
    int bad = 0;
    for (int i = t; i < 4096; i += 256)
        if (((xu[i] >> 7) & 0xFFu) > 0x9Fu) bad = 1;
    if (bad) atomicOr(&s, 1);
    __syncthreads();
    if (t == 0) flag[0] = s;
}

// ---------------------------------------------------------------------------
// K1 (k_attn): per (n, 32-px tile): double-buffered staging of x transposed
// [px][c] + W [k][c] (bf16, +1-chunk register prefetch), per-px sumsq, MFMA
// logits (M=32px, N=32k, Kdim=1024c), scale by rnorm, softmax over k,
// write attn bf16 + asum + rnorm. grid 512 = n*32 + pt, block 256.
// ---------------------------------------------------------------------------
template <typename T>
__device__ __forceinline__ void attn_body(const T* __restrict__ x,
                                          const T* __restrict__ w,
                                          float* __restrict__ rnorm_ws,
                                          unsigned short* __restrict__ attn_g,
                                          float* __restrict__ asum) {
    __shared__ __align__(16) unsigned short xt[2][32 * 136];    // [px][c] pad
    __shared__ __align__(16) unsigned short w_lds[2][32 * 136]; // [k][c] pad
    __shared__ float red[32 * 32];       // [c-group][px]
    __shared__ float lg[32 * 33];        // [px][k]
    __shared__ float inv_lds[32];
    __shared__ float rnorm_lds[32];
    const int b = blockIdx.x, t = threadIdx.x;
    const int n = b >> 5, pbase = (b & 31) * 32;
    const int lane = t & 63, wid = t >> 6;
    const int quad = lane >> 4, l15 = lane & 15;
    const int mt = wid & 1, nt = wid >> 1;   // wave -> (px-tile, k-tile)

    const size_t xb = (size_t)n * CC * PP + pbase;
    float ss0 = 0.f, ss1 = 0.f, ss2 = 0.f, ss3 = 0.f;
    f32x4 acc = {0.f, 0.f, 0.f, 0.f};

    const int pxg = 4 * (t & 7);      // this thread's 4 pixels (local)
    const int crow = t >> 3;          // base c-row (0..31); also W k-row
    const int wcg = (t & 7) * 16;     // W staging: 16 c's

    // prefetch chunk 0 into registers
    float4 xr[4], wr[4];
    #pragma unroll
    for (int pass = 0; pass < 4; ++pass)
        xr[pass] = IO<T>::ld4(&x[xb + (size_t)(crow + 32 * pass) * PP + pxg]);
    #pragma unroll
    for (int j = 0; j < 4; ++j)
        wr[j] = IO<T>::ld4(&w[crow * CC + wcg + 4 * j]);

    #pragma unroll 2
    for (int ch = 0; ch < 8; ++ch) {
        const int buf = ch & 1;
        // stage current regs -> LDS buf (with bf16 convert + sumsq accumulate)
        #pragma unroll
        for (int pass = 0; pass < 4; ++pass) {
            const int cl = crow + 32 * pass;          // 0..127 chunk-local
            const float4 v = xr[pass];
            ss0 += v.x * v.x; ss1 += v.y * v.y; ss2 += v.z * v.z; ss3 += v.w * v.w;
            xt[buf][(pxg + 0) * 136 + cl] = f2bf(v.x);
            xt[buf][(pxg + 1) * 136 + cl] = f2bf(v.y);
            xt[buf][(pxg + 2) * 136 + cl] = f2bf(v.z);
            xt[buf][(pxg + 3) * 136 + cl] = f2bf(v.w);
        }
        #pragma unroll
        for (int j = 0; j < 4; ++j) {
            const float4 v = wr[j];
            ushort4 u;
            u.x = f2bf(v.x); u.y = f2bf(v.y); u.z = f2bf(v.z); u.w = f2bf(v.w);
            *(ushort4*)&w_lds[buf][crow * 136 + wcg + 4 * j] = u;
        }
        // issue next-chunk loads; they stay in flight across the raw barrier
        if (ch < 7) {
            const int c0 = (ch + 1) * 128;
            #pragma unroll
            for (int pass = 0; pass < 4; ++pass)
                xr[pass] = IO<T>::ld4(&x[xb + (size_t)(c0 + crow + 32 * pass) * PP + pxg]);
            #pragma unroll
            for (int j = 0; j < 4; ++j)
                wr[j] = IO<T>::ld4(&w[crow * CC + c0 + wcg + 4 * j]);
        }
        wg_sync_fast();   // lgkmcnt(0) + s_barrier: stage visible, loads in flight
        #pragma unroll
        for (int ks = 0; ks < 4; ++ks) {
            const bf16x8 av = *(const bf16x8*)&xt[buf][(mt * 16 + l15) * 136 + ks * 32 + quad * 8];
            const bf16x8 bv = *(const bf16x8*)&w_lds[buf][(nt * 16 + l15) * 136 + ks * 32 + quad * 8];
            acc = __builtin_amdgcn_mfma_f32_16x16x32_bf16(av, bv, acc, 0, 0, 0);
        }
        // no trailing barrier: next iter stages the OTHER buffer; the barrier
        // above (whose lgkmcnt covers this iter's ds_reads next time around)
        // orders read(ch) vs write(ch+2).
    }
    // reduce sumsq: red[c-group][px]
    red[crow * 32 + pxg + 0] = ss0;
    red[crow * 32 + pxg + 1] = ss1;
    red[crow * 32 + pxg + 2] = ss2;
    red[crow * 32 + pxg + 3] = ss3;
    __syncthreads();
    if (t < 32) {
        float s = 0.f;
        #pragma unroll
        for (int g = 0; g < 32; ++g) s += red[g * 32 + t];
        const float r = 1.0f / fmaxf(sqrtf(s), EPSF);
        rnorm_lds[t] = r;
        rnorm_ws[n * PP + pbase + t] = r;
    }
    __syncthreads();
    // write logits (scaled by rnorm) to LDS: D row=px(local in tile), col=k
    #pragma unroll
    for (int reg = 0; reg < 4; ++reg) {
        const int px = mt * 16 + quad * 4 + reg;
        lg[px * 33 + nt * 16 + l15] = acc[reg] * rnorm_lds[px];
    }
    __syncthreads();
    if (t < 32) {
        float m = -1e30f;
        #pragma unroll
        for (int k = 0; k < KK; ++k) m = fmaxf(m, lg[t * 33 + k]);
        float s = 0.f;
        #pragma unroll
        for (int k = 0; k < KK; ++k) {
            const float e = expf(lg[t * 33 + k] - m);
            lg[t * 33 + k] = e;
            s += e;
        }
        inv_lds[t] = 1.0f / s;
    }
    __syncthreads();
    // write attn bf16 (thread: k=t>>3, 4 px) + asum atomics
    {
        const int k = t >> 3;
        float s = 0.f;
        ushort4 u;
        float vv[4];
        #pragma unroll
        for (int j = 0; j < 4; ++j) {
            const int px = pxg + j;
            vv[j] = lg[px * 33 + k] * inv_lds[px];
        }
        u.x = f2bf(vv[0]); u.y = f2bf(vv[1]); u.z = f2bf(vv[2]); u.w = f2bf(vv[3]);
        s = bf2f(u.x) + bf2f(u.y) + bf2f(u.z) + bf2f(u.w);
        *(ushort4*)&attn_g[((size_t)n * KK + k) * PP + pbase + pxg] = u;
        s += __shfl_xor(s, 1, 64);
        s += __shfl_xor(s, 2, 64);
        s += __shfl_xor(s, 4, 64);
        if ((t & 7) == 0) atomicAdd(&asum[n * KK + k], s);
    }
}
__global__ __launch_bounds__(256) void k_attn(const void* __restrict__ x,
                                              const void* __restrict__ w,
                                              const int* __restrict__ flag,
                                              float* __restrict__ rnorm_ws,
                                              unsigned short* __restrict__ attn_g,
                                              float* __restrict__ asum) {
    if (*flag) attn_body<float>((const float*)x, (const float*)w, rnorm_ws, attn_g, asum);
    else       attn_body<unsigned short>((const unsigned short*)x, (const unsigned short*)w,
                                         rnorm_ws, attn_g, asum);
}

// ---------------------------------------------------------------------------
// K2 (k_vlad): per (n, 32-c tile): MFMA vlad (M=32k, N=32c, Kdim=1024p),
// double-buffered staging + 1-chunk register prefetch.
// A=attn[k][p] bf16 staged, B=x*rnorm[c][p] bf16 staged (both p-contiguous).
// Epilogue: - asum*cent, write vlad fp32, per-k sumsq atomics.
// grid 512 = n*32 + ct, block 256 (2 blocks/CU).
// ---------------------------------------------------------------------------
template <typename T>
__device__ __forceinline__ void vlad_body(const T* __restrict__ x,
                                          const T* __restrict__ cent,
                                          const float* __restrict__ rnorm_ws,
                                          const unsigned short* __restrict__ attn_g,
                                          const float* __restrict__ asum,
                                          float* __restrict__ vlad,
                                          float* __restrict__ ssqnk) {
    __shared__ __align__(16) unsigned short xt[2][32 * 136];     // [c][p] pad
    __shared__ __align__(16) unsigned short at_lds[2][32 * 136]; // [k][p] pad
    __shared__ float asum_lds[32];
    __shared__ float ssq_lds[32];
    const int b = blockIdx.x, t = threadIdx.x;
    const int n = b >> 5, cbase = (b & 31) * 32;
    const int lane = t & 63, wid = t >> 6;
    const int quad = lane >> 4, l15 = lane & 15;
    const int mt = wid & 1, nt = wid >> 1;   // wave -> (k-half, c-half)

    if (t < 32) { asum_lds[t] = asum[n * KK + t]; ssq_lds[t] = 0.f; }

    f32x4 acc = {0.f, 0.f, 0.f, 0.f};
    const size_t xb = (size_t)n * CC * PP + (size_t)cbase * PP;

    const int ak  = t >> 3, apg = (t & 7) * 16;  // attn staging: k-row, 16 p
    const int xpg = 4 * (t & 31);                // x staging: 4 p
    const int xc  = t >> 5;                      // x staging: base c-row (+8*pass)

    // prefetch chunk 0
    uint4 a0, a1; float4 xr[4]; float4 rn;
    {
        const size_t abase = ((size_t)n * KK + ak) * PP + apg;
        a0 = *(const uint4*)&attn_g[abase];
        a1 = *(const uint4*)&attn_g[abase + 8];
        rn = *(const float4*)&rnorm_ws[n * PP + xpg];
        #pragma unroll
        for (int pass = 0; pass < 4; ++pass)
            xr[pass] = IO<T>::ld4(&x[xb + (size_t)(xc + 8 * pass) * PP + xpg]);
    }

    #pragma unroll 2
    for (int pc = 0; pc < 8; ++pc) {
        const int buf = pc & 1;
        // stage attn chunk: 32k x 128p (pure copy, already bf16)
        *(uint4*)&at_lds[buf][ak * 136 + apg]     = a0;
        *(uint4*)&at_lds[buf][ak * 136 + apg + 8] = a1;
        // stage x-hat chunk: 32c x 128p
        #pragma unroll
        for (int pass = 0; pass < 4; ++pass) {
            const int ci = xc + 8 * pass;
            const float4 v = xr[pass];
            ushort4 u;
            u.x = f2bf(v.x * rn.x); u.y = f2bf(v.y * rn.y);
            u.z = f2bf(v.z * rn.z); u.w = f2bf(v.w * rn.w);
            *(ushort4*)&xt[buf][ci * 136 + xpg] = u;
        }
        // prefetch next chunk
        if (pc < 7) {
            const int p0 = (pc + 1) * 128;
            const size_t abase = ((size_t)n * KK + ak) * PP + p0 + apg;
            a0 = *(const uint4*)&attn_g[abase];
            a1 = *(const uint4*)&attn_g[abase + 8];
            rn = *(const float4*)&rnorm_ws[n * PP + p0 + xpg];
            #pragma unroll
            for (int pass = 0; pass < 4; ++pass)
                xr[pass] = IO<T>::ld4(&x[xb + (size_t)(xc + 8 * pass) * PP + p0 + xpg]);
        }
        wg_sync_fast();
        #pragma unroll
        for (int ks = 0; ks < 4; ++ks) {
            const bf16x8 av = *(const bf16x8*)&at_lds[buf][(mt * 16 + l15) * 136 + ks * 32 + quad * 8];
            const bf16x8 bv = *(const bf16x8*)&xt[buf][(nt * 16 + l15) * 136 + ks * 32 + quad * 8];
            acc = __builtin_amdgcn_mfma_f32_16x16x32_bf16(av, bv, acc, 0, 0, 0);
        }
    }
    // epilogue: D row = k(local), col = c(local)
    const int cg = cbase + nt * 16 + l15;
    #pragma unroll
    for (int reg = 0; reg < 4; ++reg) {
        const int k = mt * 16 + quad * 4 + reg;
        const float A = asum_lds[k];
        const float v0 = acc[reg] - A * IO<T>::ld(&cent[k * CC + cg]);
        vlad[((size_t)n * KK + k) * CC + cg] = v0;
        float s = v0 * v0;
        s += __shfl_xor(s, 1, 64);
        s += __shfl_xor(s, 2, 64);
        s += __shfl_xor(s, 4, 64);
        s += __shfl_xor(s, 8, 64);
        if (l15 == 0) atomicAdd(&ssq_lds[k], s);
    }
    __syncthreads();
    if (t < 32) atomicAdd(&ssqnk[n * KK + t], ssq_lds[t]);
}
__global__ __launch_bounds__(256) void k_vlad(const void* __restrict__ x,
                                              const void* __restrict__ cent,
                                              const int* __restrict__ flag,
                                              const float* __restrict__ rnorm_ws,
                                              const unsigned short* __restrict__ attn_g,
                                              const float* __restrict__ asum,
                                              float* __restrict__ vlad,
                                              float* __restrict__ ssqnk) {
    if (*flag) vlad_body<float>((const float*)x, (const float*)cent, rnorm_ws, attn_g,
                                asum, vlad, ssqnk);
    else       vlad_body<unsigned short>((const unsigned short*)x, (const unsigned short*)cent,
                                         rnorm_ws, attn_g, asum, vlad, ssqnk);
}

// ---------------------------------------------------------------------------
// K3 (k_out): factors computed inline from ssqnk (wave 0: 32 L2-hot loads,
// same arithmetic as the old k_factors), then out = vlad*rintra*rglob cast
// to out dtype. grid N*K, 256 thr.
// ---------------------------------------------------------------------------
__global__ __launch_bounds__(256) void k_out(const float* __restrict__ vlad,
                                             const float* __restrict__ ssqnk,
                                             const int* __restrict__ flag,
                                             void* __restrict__ out) {
    __shared__ float fsh;
    const int b = blockIdx.x, t = threadIdx.x;
    const int n = b >> 5, k = b & 31;
    if (t < 64) {
        const float s = (t < 32) ? ssqnk[n * KK + t] : 0.f;
        const float r = 1.0f / fmaxf(sqrtf(s), EPSF);
        float g = s * r * r;
        #pragma unroll
        for (int off = 32; off > 0; off >>= 1) g += __shfl_down(g, off, 64);
        const float rk = __shfl(r, k, 64);
        if (t == 0) fsh = rk * (1.0f / fmaxf(sqrtf(g), EPSF));
    }
    __syncthreads();
    const float f = fsh;
    const float4 v = ((const float4*)(vlad + (size_t)b * CC))[t];
    if (*flag) {
        float4 o; o.x = v.x * f; o.y = v.y * f; o.z = v.z * f; o.w = v.w * f;
        ((float4*)((float*)out + (size_t)b * CC))[t] = o;
    } else {
        ushort4 u;
        u.x = f2bf(v.x * f); u.y = f2bf(v.y * f);
        u.z = f2bf(v.z * f); u.w = f2bf(v.w * f);
        ((ushort4*)((unsigned short*)out + (size_t)b * CC))[t] = u;
    }
}

extern "C" void kernel_launch(void* const* d_in, const int* in_sizes, int n_in,
                              void* d_out, int out_size, void* d_ws, size_t ws_size,
                              hipStream_t stream) {
    const void* x    = d_in[0];
    const void* w    = d_in[1];
    const void* cent = d_in[2];

    float* ws       = (float*)d_ws;
    float* rnorm_ws = ws;                          // 16384
    float* vlad     = rnorm_ws + NB * PP;          // 524288
    float* asum     = vlad + NB * KK * CC;         // 512
    float* ssqnk    = asum + NB * KK;              // 512 (contiguous after asum)
    float* rintra   = ssqnk + NB * KK;             // kept for layout compat (unused)
    float* rglob    = rintra + NB * KK;            // unused
    int*   flag     = (int*)(rglob + NB);          // 1 (+ pad)
    unsigned short* attn_g = (unsigned short*)(flag + 4);   // 512K ushorts
    (void)rintra; (void)rglob;

    k_detect<<<1, 256, 0, stream>>>((const unsigned short*)x, flag, asum); // zeroes asum+ssqnk
    k_attn<<<NB * 32, 256, 0, stream>>>(x, w, flag, rnorm_ws, attn_g, asum);
    k_vlad<<<NB * 32, 256, 0, stream>>>(x, cent, flag, rnorm_ws, attn_g, asum, vlad, ssqnk);
    k_out<<<NB * KK, 256, 0, stream>>>(vlad, ssqnk, flag, d_out);
}